// Round 11
// baseline (265.654 us; speedup 1.0000x reference)
//
#include <hip/hip_runtime.h>
#include <math.h>

#define R_    8192
#define D_    128
#define RD    (R_ * D_)
#define NXg   160
#define NYg   160
#define NZg   128
#define CSg   (NXg * NYg * NZg)
#define WIDm  128
#define K0C   12
#define LAMc  0.01f
#define VSRc  2.0f

// frag table sizes (shorts): w1f | w0kf | w2f contiguous
#define W1F_N   16384
#define W0KF_N  2048
#define W2F_N   4096
#define WTAB_N  (W1F_N + W0KF_N + W2F_N)   // 22528 shorts = 45056 B
#define LW1     0
#define LW0K    W1F_N
#define LW2     (W1F_N + W0KF_N)

#define PACK_BLKS   (CSg / 1024)           // 3200 (4 voxels/thread, R9 config)
#define EPREP_BLKS  (R_ / 2)               // 4096 (2 rays / 256-thr block)
#define WTAB_BLKS   (WTAB_N / 256)         // 88

typedef __attribute__((ext_vector_type(8)))  short   short8v;
typedef __attribute__((ext_vector_type(4)))  float   f32x4;
typedef __attribute__((ext_vector_type(16))) float   f32x16;
typedef __attribute__((ext_vector_type(2)))  int     int2v;
typedef __attribute__((ext_vector_type(4)))  int     int4v;
typedef __attribute__((ext_vector_type(4)))  unsigned short ushort4v;
typedef __attribute__((ext_vector_type(8)))  unsigned short ushort8v;

static __device__ __forceinline__ unsigned short f2b(float f) {
    union { float f; unsigned int u; } v; v.f = f;
    unsigned int r = v.u + 0x7fffu + ((v.u >> 16) & 1u);   // RNE
    return (unsigned short)(r >> 16);
}
static __device__ __forceinline__ float b2f(unsigned short u) {
    union { unsigned int u; float f; } v; v.u = ((unsigned int)u) << 16;
    return v.f;
}
static __device__ __forceinline__ unsigned int pk2(float lo, float hi) {
    unsigned int r;
    asm("v_cvt_pk_bf16_f32 %0, %1, %2" : "=v"(r) : "v"(lo), "v"(hi));
    return r;
}
static __device__ __forceinline__ short8v as_s8(int4v v) {
    union { int4v i; short8v s; } u; u.i = v; return u.s;
}

// =============== prep device helpers ===============================================
static __device__ __forceinline__ void eprep_body(
    int r, int j, const float* __restrict__ rays_d,
    const float* __restrict__ w0, const float* __restrict__ b0, float* __restrict__ e)
{
    float d0 = rays_d[r * 3 + 0], d1 = rays_d[r * 3 + 1], d2 = rays_d[r * 3 + 2];
    float nrm = sqrtf(d0 * d0 + d1 * d1 + d2 * d2) + 1e-8f;
    float v[3] = { d0 / nrm, d1 / nrm, d2 / nrm };
    float x[27];
    x[0] = v[0]; x[1] = v[1]; x[2] = v[2];
#pragma unroll
    for (int c = 0; c < 3; ++c)
#pragma unroll
        for (int f = 0; f < 4; ++f) {
            float ang = v[c] * (float)(1 << f);
            x[3 + c * 4 + f]  = sinf(ang);
            x[15 + c * 4 + f] = cosf(ang);
        }
    float acc = b0[j];
#pragma unroll
    for (int m = 0; m < 27; ++m) acc = fmaf(x[m], w0[m * WIDm + j], acc);
    e[r * WIDm + j] = acc;
}

static __device__ __forceinline__ void wtab_body(
    int t, const float* __restrict__ w0, const float* __restrict__ w1,
    const float* __restrict__ w2, unsigned short* __restrict__ wtab)
{
    if (t < W1F_N) {                       // w1 A-frags: tiles (mt,ks), 4x8
        int tile = t >> 9, l = (t >> 3) & 63, j = t & 7;
        int mt = tile >> 3, ks = tile & 7;
        int m = mt * 32 + (l & 31);
        int k = ks * 16 + 8 * (l >> 5) + j;
        wtab[LW1 + t] = f2b(w1[k * WIDm + m]);
    } else if (t < W1F_N + W0KF_N) {       // w0[27:39] A-frags: 4 mt tiles, K=16 (pad)
        int u = t - W1F_N;
        int mt = u >> 9, l = (u >> 3) & 63, j = u & 7;
        int m = mt * 32 + (l & 31);
        int k = 8 * (l >> 5) + j;
        wtab[LW0K + u] = f2b(k < K0C ? w0[(27 + k) * WIDm + m] : 0.0f);
    } else if (t < WTAB_N) {               // w2[:,0:3] A-frags: 8 ks tiles, M=32 (pad)
        int u = t - W1F_N - W0KF_N;
        int ks = u >> 9, l = (u >> 3) & 63, j = u & 7;
        int m = l & 31;
        int k = ks * 16 + 8 * (l >> 5) + j;
        wtab[LW2 + u] = f2b(m < 3 ? w2[k * 78 + m] : 0.0f);
    }
}

// ---------------- merged: pack (R9 4-vox form, nt stores) + e-prep + wtab ----------
__global__ __launch_bounds__(256) void k_pack_prep(
    const float* __restrict__ dg, const float* __restrict__ pg,
    const float* __restrict__ kg, unsigned short* __restrict__ vox,
    const float* __restrict__ rays_d,
    const float* __restrict__ w0, const float* __restrict__ b0,
    const float* __restrict__ w1, const float* __restrict__ w2,
    float* __restrict__ e, unsigned short* __restrict__ wtab)
{
    const int bid = blockIdx.x;
    const int tid = threadIdx.x;
    if (bid < PACK_BLKS) {
        // ---- pack: chunk-transposed, line-perfect loads AND stores ----
        const int g   = tid & 3;
        const int s2  = tid >> 2;
        const float* pl[8];
        bool padq[8];
#pragma unroll
        for (int q = 0; q < 8; ++q) {
            int ch = 8 * g + q;
            padq[q] = (ch >= 29);
            pl[q] = (ch == 0) ? dg
                  : (ch < 17) ? pg + (size_t)(ch - 1) * CSg
                  : (ch < 29) ? kg + (size_t)(ch - 17) * CSg
                  : dg;
        }
#pragma unroll
        for (int it = 0; it < 4; ++it) {
            int vofs = (bid * 4 + it) * 256 + 4 * s2;
            f32x4 L[8];
#pragma unroll
            for (int q = 0; q < 8; ++q) {
                f32x4 v = __builtin_nontemporal_load((const f32x4*)(pl[q] + vofs));
                if (padq[q]) v = f32x4{0.0f, 0.0f, 0.0f, 0.0f};
                L[q] = v;
            }
#pragma unroll
            for (int k = 0; k < 4; ++k) {
                int4v chunk;
#pragma unroll
                for (int h2 = 0; h2 < 4; ++h2)
                    chunk[h2] = (int)pk2(L[2 * h2][k], L[2 * h2 + 1][k]);
                __builtin_nontemporal_store(
                    chunk, (int4v*)((char*)vox + (size_t)(vofs + k) * 64 + g * 16));
            }
        }
    } else if (bid < PACK_BLKS + EPREP_BLKS) {
        int r = (bid - PACK_BLKS) * 2 + (tid >> 7);
        eprep_body(r, tid & 127, rays_d, w0, b0, e);
    } else {
        int t = (bid - PACK_BLKS - EPREP_BLKS) * 256 + tid;
        wtab_body(t, w0, w1, w2, wtab);
    }
}

// ---------------- standalone prep (fallback path only) -----------------------------
__global__ __launch_bounds__(512) void k_prep_all(
    const float* __restrict__ rays_d,
    const float* __restrict__ w0, const float* __restrict__ b0,
    const float* __restrict__ w1, const float* __restrict__ w2,
    float* __restrict__ e, unsigned short* __restrict__ wtab)
{
    int bid = blockIdx.x;
    if (bid < R_ / 4) {
        int r = bid * 4 + (threadIdx.x >> 7);
        eprep_body(r, threadIdx.x & 127, rays_d, w0, b0, e);
    } else {
        int t = (bid - R_ / 4) * 512 + threadIdx.x;
        wtab_body(t, w0, w1, w2, wtab);
    }
}

// =============== shared helpers =====================================================
static __device__ __forceinline__ void sample_coords(
    int sid, const float* __restrict__ rays_o, const float* __restrict__ rays_d,
    int& ix, int& iy, int& iz, float& fx, float& fy, float& fz)
{
    int r = sid >> 7;
    int s = sid & 127;
    float t = s * (1.0f / 127.0f);
    float px = fminf(fmaxf(rays_o[r * 3 + 0] + rays_d[r * 3 + 0] * t, 0.0f), 1.0f);
    float py = fminf(fmaxf(rays_o[r * 3 + 1] + rays_d[r * 3 + 1] * t, 0.0f), 1.0f);
    float pz = fminf(fmaxf(rays_o[r * 3 + 2] + rays_d[r * 3 + 2] * t, 0.0f), 1.0f);
    float gx = px * (float)(NXg - 1);
    float gy = py * (float)(NYg - 1);
    float gz = pz * (float)(NZg - 1);
    ix = min((int)gx, NXg - 2);
    iy = min((int)gy, NYg - 2);
    iz = min((int)gz, NZg - 2);
    fx = gx - (float)ix;
    fy = gy - (float)iy;
    fz = gz - (float)iz;
}

static __device__ __forceinline__ float density_alpha(
    int s, const float* acc, float gfd0, const float* __restrict__ act_shift)
{
    float z = acc[0] + gfd0;
#pragma unroll
    for (int i = 0; i < 4; ++i) {
        float pa = acc[1 + 4 * i + 0], pb = acc[1 + 4 * i + 1];
        float pc = acc[1 + 4 * i + 2], pd = acc[1 + 4 * i + 3];
        float sg = 1.0f / (1.0f + expf(-pd));
        z += pa * tanhf(pb * z + pc) * sg;
    }
    float den = z + act_shift[s];
    float sp = fmaxf(den, 0.0f) + log1pf(expf(-fabsf(den)));
    return 1.0f - expf(-sp * VSRc);
}

static __device__ __forceinline__ void finish_sample(
    int sid, int s, const float* acc, float gfd0,
    const float* __restrict__ act_shift,
    float* __restrict__ alpha_ws, unsigned short* __restrict__ k0b)
{
    alpha_ws[sid] = density_alpha(s, acc, gfd0, act_shift);
    ushort8v lo, hi;
#pragma unroll
    for (int c = 0; c < 8; ++c) lo[c] = f2b(acc[17 + c]);
#pragma unroll
    for (int c = 0; c < 8; ++c) hi[c] = (c < 4) ? f2b(acc[25 + c]) : (unsigned short)0;
    *(ushort8v*)(k0b + (size_t)sid * 16)     = lo;
    *(ushort8v*)(k0b + (size_t)sid * 16 + 8) = hi;
}

// ---------------- K1a: AoS gather — issue ALL 32 loads, then accumulate ------------
__global__ __launch_bounds__(256) void k_gather_aos(
    const float* __restrict__ rays_o, const float* __restrict__ rays_d,
    const unsigned short* __restrict__ vox,
    const float* __restrict__ gfd, const float* __restrict__ act_shift,
    float* __restrict__ alpha_ws, unsigned short* __restrict__ k0b)
{
    int sid = blockIdx.x * 256 + threadIdx.x;
    if (sid >= RD) return;
    int ix, iy, iz; float fx, fy, fz;
    sample_coords(sid, rays_o, rays_d, ix, iy, iz, fx, fy, fz);

    const unsigned short* base = vox + ((size_t)(ix * NYg + iy) * NZg + iz) * 32;
    const size_t qoff[4] = { 0, (size_t)NZg * 32, (size_t)NYg * NZg * 32,
                             (size_t)(NYg + 1) * NZg * 32 };
    float wxy[4];
    wxy[0] = (1.0f - fx) * (1.0f - fy);
    wxy[1] = (1.0f - fx) * fy;
    wxy[2] = fx * (1.0f - fy);
    wxy[3] = fx * fy;
    float wz0 = 1.0f - fz, wz1 = fz;

    // issue all 4 corners x 128 B (dz pair) = 32 x b128 loads before any use
    ushort8v v[4][8];
#pragma unroll
    for (int q = 0; q < 4; ++q) {
        const ushort8v* pv = (const ushort8v*)(base + qoff[q]);
#pragma unroll
        for (int i = 0; i < 8; ++i) v[q][i] = pv[i];
    }

    float acc[29];
#pragma unroll
    for (int c = 0; c < 29; ++c) acc[c] = 0.0f;
#pragma unroll
    for (int q = 0; q < 4; ++q) {
#pragma unroll
        for (int dz = 0; dz < 2; ++dz) {
            float w = wxy[q] * (dz ? wz1 : wz0);
            ushort8v v0 = v[q][dz * 4 + 0], v1 = v[q][dz * 4 + 1];
            ushort8v v2 = v[q][dz * 4 + 2], v3 = v[q][dz * 4 + 3];
#pragma unroll
            for (int i = 0; i < 8; ++i) acc[i]      = fmaf(w, b2f(v0[i]), acc[i]);
#pragma unroll
            for (int i = 0; i < 8; ++i) acc[8 + i]  = fmaf(w, b2f(v1[i]), acc[8 + i]);
#pragma unroll
            for (int i = 0; i < 8; ++i) acc[16 + i] = fmaf(w, b2f(v2[i]), acc[16 + i]);
#pragma unroll
            for (int i = 0; i < 5; ++i) acc[24 + i] = fmaf(w, b2f(v3[i]), acc[24 + i]);
        }
    }
    finish_sample(sid, sid & 127, acc, gfd[0] * LAMc, act_shift, alpha_ws, k0b);
}

// ---------------- K1b: SoA f32 gather (fallback when ws too small) -----------------
__global__ void k_gather_soa(
    const float* __restrict__ rays_o, const float* __restrict__ rays_d,
    const float* __restrict__ dg,  const float* __restrict__ pg,
    const float* __restrict__ kg,  const float* __restrict__ gfd,
    const float* __restrict__ act_shift,
    float* __restrict__ alpha_ws, unsigned short* __restrict__ k0b)
{
    int sid = blockIdx.x * 256 + threadIdx.x;
    if (sid >= RD) return;
    int ix, iy, iz; float fx, fy, fz;
    sample_coords(sid, rays_o, rays_d, ix, iy, iz, fx, fy, fz);

    int base = (ix * NYg + iy) * NZg + iz;
    int off[4] = { base, base + NZg, base + NYg * NZg, base + NYg * NZg + NZg };
    float wxy[4];
    wxy[0] = (1.0f - fx) * (1.0f - fy);
    wxy[1] = (1.0f - fx) * fy;
    wxy[2] = fx * (1.0f - fy);
    wxy[3] = fx * fy;
    float wz0 = 1.0f - fz, wz1 = fz;

    auto tri = [&](const float* __restrict__ g, int c) -> float {
        float a = 0.0f;
        const float* gc = g + (size_t)c * CSg;
#pragma unroll
        for (int q = 0; q < 4; ++q) {
            const float* p = gc + off[q];
            a += (p[0] * wz0 + p[1] * wz1) * wxy[q];
        }
        return a;
    };
    float acc[29];
    acc[0] = tri(dg, 0);
#pragma unroll
    for (int c = 0; c < 16; ++c) acc[1 + c] = tri(pg, c);
#pragma unroll
    for (int c = 0; c < K0C; ++c) acc[17 + c] = tri(kg, c);
    finish_sample(sid, sid & 127, acc, gfd[0] * LAMc, act_shift, alpha_ws, k0b);
}

// ---------------- K2: MFMA MLP, wave-per-ray (4 rays/block) + in-wave scan ---------
// C/D layout (32x32): col = lane&31, row = (r&3) + 8*(r>>2) + 4*(lane>>5)  [m74/m101]
struct BPair { int4v lo, hi; };
static __device__ __forceinline__ BPair ttile(const f32x16 v) {
    unsigned p[8];
#pragma unroll
    for (int q = 0; q < 8; ++q) p[q] = pk2(v[2 * q], v[2 * q + 1]);
    int2v a = __builtin_amdgcn_permlane32_swap((int)p[0], (int)p[2], false, false);
    int2v b = __builtin_amdgcn_permlane32_swap((int)p[1], (int)p[3], false, false);
    int2v c = __builtin_amdgcn_permlane32_swap((int)p[4], (int)p[6], false, false);
    int2v d = __builtin_amdgcn_permlane32_swap((int)p[5], (int)p[7], false, false);
    BPair r;
    r.lo = int4v{ a.x, b.x, a.y, b.y };
    r.hi = int4v{ c.x, d.x, c.y, d.y };
    return r;
}

__global__ __launch_bounds__(256) void k_mlp_scan4(
    const unsigned short* __restrict__ k0b, const float* __restrict__ e,
    const unsigned short* __restrict__ wtab,
    const float* __restrict__ b1, const float* __restrict__ b2,
    const float* __restrict__ gfr, const float* __restrict__ alpha_ws,
    float* __restrict__ out)
{
    __shared__ unsigned short wlds[WTAB_N];   // 45056 B, staged once per block
    __shared__ float rgb_lds[4][D_][4];       // 8192 B, wave-local strips
#pragma unroll
    for (int it = 0; it < WTAB_N / (256 * 8); ++it) {
        int i = (it * 256 + threadIdx.x) * 8;
        *(ushort8v*)&wlds[i] = *(const ushort8v*)&wtab[i];
    }
    __syncthreads();

    const int lane = threadIdx.x & 63;
    const int wid  = threadIdx.x >> 6;
    const int n    = lane & 31;
    const int h    = lane >> 5;
    const int ray  = blockIdx.x * 4 + wid;    // one wave = one ray

    for (int t = 0; t < 4; ++t) {
        const int sid = ray * D_ + t * 32 + n;

        // ---- layer 0: C-init = e[ray][.] (emb@w0[0:27]+b0), A = w0k frags ----
        f32x16 acc0[4];
#pragma unroll
        for (int mt = 0; mt < 4; ++mt) {
            const f32x4* ep = (const f32x4*)(e + (size_t)ray * WIDm + mt * 32 + 4 * h);
#pragma unroll
            for (int rr = 0; rr < 4; ++rr) {
                f32x4 ev = ep[2 * rr];
#pragma unroll
                for (int q = 0; q < 4; ++q) acc0[mt][rr * 4 + q] = ev[q];
            }
        }
        short8v bk = *(const short8v*)(k0b + (size_t)sid * 16 + h * 8);
#pragma unroll
        for (int mt = 0; mt < 4; ++mt) {
            short8v af = *(const short8v*)&wlds[LW0K + (mt * 64 + lane) * 8];
            acc0[mt] = __builtin_amdgcn_mfma_f32_32x32x16_bf16(af, bk, acc0[mt], 0, 0, 0);
        }
        int4v bw[8];
#pragma unroll
        for (int mt = 0; mt < 4; ++mt) {
            f32x16 hv;
#pragma unroll
            for (int r = 0; r < 16; ++r) hv[r] = fmaxf(acc0[mt][r], 0.0f);
            BPair tt = ttile(hv);
            bw[2 * mt]     = tt.lo;
            bw[2 * mt + 1] = tt.hi;
        }

        // ---- layer 1 ----
        f32x16 acc1[4];
#pragma unroll
        for (int mt = 0; mt < 4; ++mt) {
            const f32x4* bp = (const f32x4*)(b1 + mt * 32 + 4 * h);
#pragma unroll
            for (int rr = 0; rr < 4; ++rr) {
                f32x4 bv = bp[2 * rr];
#pragma unroll
                for (int q = 0; q < 4; ++q) acc1[mt][rr * 4 + q] = bv[q];
            }
        }
#pragma unroll
        for (int mt = 0; mt < 4; ++mt)
#pragma unroll
            for (int ks = 0; ks < 8; ++ks) {
                short8v af = *(const short8v*)&wlds[LW1 + ((mt * 8 + ks) * 64 + lane) * 8];
                acc1[mt] = __builtin_amdgcn_mfma_f32_32x32x16_bf16(af, as_s8(bw[ks]), acc1[mt], 0, 0, 0);
            }
        int4v cw[8];
#pragma unroll
        for (int mt = 0; mt < 4; ++mt) {
            f32x16 hv;
#pragma unroll
            for (int r = 0; r < 16; ++r) hv[r] = fmaxf(acc1[mt][r], 0.0f);
            BPair tt = ttile(hv);
            cw[2 * mt]     = tt.lo;
            cw[2 * mt + 1] = tt.hi;
        }

        // ---- layer 2: rgb rows 0..2 ----
        f32x16 acc2;
#pragma unroll
        for (int r = 0; r < 16; ++r) acc2[r] = 0.0f;
#pragma unroll
        for (int ks = 0; ks < 8; ++ks) {
            short8v af = *(const short8v*)&wlds[LW2 + (ks * 64 + lane) * 8];
            acc2 = __builtin_amdgcn_mfma_f32_32x32x16_bf16(af, as_s8(cw[ks]), acc2, 0, 0, 0);
        }
        if (h == 0) {   // sample t*32+n; wave-local LDS, DS in-order -> no barrier
#pragma unroll
            for (int c = 0; c < 3; ++c) {
                float v = acc2[c] + b2[c] + gfr[c] * LAMc;
                rgb_lds[wid][t * 32 + n][c] = 1.0f / (1.0f + expf(-v));
            }
        }
    }

    // ---- in-wave transmittance scan + weighted reduce ----
    int base = ray * D_ + lane * 2;
    float a0 = alpha_ws[base];
    float a1 = alpha_ws[base + 1];
    float q0 = 1.0f - a0 + 1e-10f;
    float q1 = 1.0f - a1 + 1e-10f;
    float p = q0 * q1;

    float incl = p;
#pragma unroll
    for (int o = 1; o < 64; o <<= 1) {
        float v = __shfl_up(incl, o);
        if (lane >= o) incl *= v;
    }
    float excl = __shfl_up(incl, 1);
    if (lane == 0) excl = 1.0f;
    float Tlast = __shfl(incl, 63);

    float w0s = a0 * excl;
    float w1s = a1 * excl * q0;

    float sums[3];
#pragma unroll
    for (int c = 0; c < 3; ++c) {
        float sc = w0s * rgb_lds[wid][2 * lane][c] + w1s * rgb_lds[wid][2 * lane + 1][c];
#pragma unroll
        for (int o = 32; o >= 1; o >>= 1) sc += __shfl_xor(sc, o);
        sums[c] = sc;
    }
    if (lane == 0) {
#pragma unroll
        for (int c = 0; c < 3; ++c) out[ray * 3 + c] = sums[c] + Tlast;
    }
}

extern "C" void kernel_launch(void* const* d_in, const int* in_sizes, int n_in,
                              void* d_out, int out_size, void* d_ws, size_t ws_size,
                              hipStream_t stream) {
    const float* rays_o    = (const float*)d_in[0];
    const float* rays_d    = (const float*)d_in[1];
    const float* dg        = (const float*)d_in[2];
    const float* pg        = (const float*)d_in[3];
    const float* kg        = (const float*)d_in[4];
    const float* gfd       = (const float*)d_in[5];
    const float* gfr       = (const float*)d_in[6];
    const float* w0        = (const float*)d_in[7];
    const float* b0        = (const float*)d_in[8];
    const float* w1        = (const float*)d_in[9];
    const float* b1        = (const float*)d_in[10];
    const float* w2        = (const float*)d_in[11];
    const float* b2        = (const float*)d_in[12];
    const float* act_shift = (const float*)d_in[13];
    float* out = (float*)d_out;

    float* ws = (float*)d_ws;
    float*          alpha_ws = ws;                               // RD f32
    unsigned short* k0b      = (unsigned short*)(ws + 4 * (size_t)RD);   // RD*16 u16
    float*          e_ws     = ws + 12 * (size_t)RD;             // RD f32
    unsigned short* wtab     = (unsigned short*)(ws + 13 * (size_t)RD);  // 22528 u16
    size_t frag_end = 13 * (size_t)RD * 4 + (size_t)WTAB_N * 2;
    size_t vox_off  = (frag_end + 63) & ~(size_t)63;
    unsigned short* vox = (unsigned short*)((char*)d_ws + vox_off);
    size_t need = vox_off + (size_t)CSg * 64;
    bool use_aos = (ws_size >= need);

    if (use_aos) {
        k_pack_prep<<<dim3(PACK_BLKS + EPREP_BLKS + WTAB_BLKS), dim3(256), 0, stream>>>(
            dg, pg, kg, vox, rays_d, w0, b0, w1, w2, e_ws, wtab);
        k_gather_aos<<<dim3(RD / 256), dim3(256), 0, stream>>>(
            rays_o, rays_d, vox, gfd, act_shift, alpha_ws, k0b);
    } else {
        k_prep_all<<<dim3(R_ / 4 + (WTAB_N + 511) / 512), dim3(512), 0, stream>>>(
            rays_d, w0, b0, w1, w2, e_ws, wtab);
        k_gather_soa<<<dim3(RD / 256), dim3(256), 0, stream>>>(
            rays_o, rays_d, dg, pg, kg, gfd, act_shift, alpha_ws, k0b);
    }
    k_mlp_scan4<<<dim3(R_ / 4), dim3(256), 0, stream>>>(
        k0b, e_ws, wtab, b1, b2, gfr, alpha_ws, out);
}

// Round 12
// 238.180 us; speedup vs baseline: 1.1153x; 1.1153x over previous
//
#include <hip/hip_runtime.h>
#include <math.h>

#define R_    8192
#define D_    128
#define RD    (R_ * D_)
#define NXg   160
#define NYg   160
#define NZg   128
#define CSg   (NXg * NYg * NZg)
#define WIDm  128
#define K0C   12
#define LAMc  0.01f
#define VSRc  2.0f

// frag table sizes (shorts): w1f | w0kf | w2f contiguous
#define W1F_N   16384
#define W0KF_N  2048
#define W2F_N   4096
#define WTAB_N  (W1F_N + W0KF_N + W2F_N)   // 22528 shorts = 45056 B
#define LW1     0
#define LW0K    W1F_N
#define LW2     (W1F_N + W0KF_N)

#define PACK_BLKS   (CSg / 2048)           // 1600 (8 voxels/thread, R10 config)
#define EPREP_BLKS  (R_ / 2)               // 4096 (2 rays / 256-thr block)
#define WTAB_BLKS   (WTAB_N / 256)         // 88

typedef __attribute__((ext_vector_type(8)))  short   short8v;
typedef __attribute__((ext_vector_type(4)))  float   f32x4;
typedef __attribute__((ext_vector_type(16))) float   f32x16;
typedef __attribute__((ext_vector_type(2)))  int     int2v;
typedef __attribute__((ext_vector_type(4)))  int     int4v;
typedef __attribute__((ext_vector_type(4)))  unsigned short ushort4v;
typedef __attribute__((ext_vector_type(8)))  unsigned short ushort8v;

static __device__ __forceinline__ unsigned short f2b(float f) {
    union { float f; unsigned int u; } v; v.f = f;
    unsigned int r = v.u + 0x7fffu + ((v.u >> 16) & 1u);   // RNE
    return (unsigned short)(r >> 16);
}
static __device__ __forceinline__ float b2f(unsigned short u) {
    union { unsigned int u; float f; } v; v.u = ((unsigned int)u) << 16;
    return v.f;
}
static __device__ __forceinline__ unsigned int pk2(float lo, float hi) {
    unsigned int r;
    asm("v_cvt_pk_bf16_f32 %0, %1, %2" : "=v"(r) : "v"(lo), "v"(hi));
    return r;
}
static __device__ __forceinline__ short8v as_s8(int4v v) {
    union { int4v i; short8v s; } u; u.i = v; return u.s;
}

// =============== prep device helpers ===============================================
static __device__ __forceinline__ void eprep_body(
    int r, int j, const float* __restrict__ rays_d,
    const float* __restrict__ w0, const float* __restrict__ b0, float* __restrict__ e)
{
    float d0 = rays_d[r * 3 + 0], d1 = rays_d[r * 3 + 1], d2 = rays_d[r * 3 + 2];
    float nrm = sqrtf(d0 * d0 + d1 * d1 + d2 * d2) + 1e-8f;
    float v[3] = { d0 / nrm, d1 / nrm, d2 / nrm };
    float x[27];
    x[0] = v[0]; x[1] = v[1]; x[2] = v[2];
#pragma unroll
    for (int c = 0; c < 3; ++c)
#pragma unroll
        for (int f = 0; f < 4; ++f) {
            float ang = v[c] * (float)(1 << f);
            x[3 + c * 4 + f]  = sinf(ang);
            x[15 + c * 4 + f] = cosf(ang);
        }
    float acc = b0[j];
#pragma unroll
    for (int m = 0; m < 27; ++m) acc = fmaf(x[m], w0[m * WIDm + j], acc);
    e[r * WIDm + j] = acc;
}

static __device__ __forceinline__ void wtab_body(
    int t, const float* __restrict__ w0, const float* __restrict__ w1,
    const float* __restrict__ w2, unsigned short* __restrict__ wtab)
{
    if (t < W1F_N) {                       // w1 A-frags: tiles (mt,ks), 4x8
        int tile = t >> 9, l = (t >> 3) & 63, j = t & 7;
        int mt = tile >> 3, ks = tile & 7;
        int m = mt * 32 + (l & 31);
        int k = ks * 16 + 8 * (l >> 5) + j;
        wtab[LW1 + t] = f2b(w1[k * WIDm + m]);
    } else if (t < W1F_N + W0KF_N) {       // w0[27:39] A-frags: 4 mt tiles, K=16 (pad)
        int u = t - W1F_N;
        int mt = u >> 9, l = (u >> 3) & 63, j = u & 7;
        int m = mt * 32 + (l & 31);
        int k = 8 * (l >> 5) + j;
        wtab[LW0K + u] = f2b(k < K0C ? w0[(27 + k) * WIDm + m] : 0.0f);
    } else if (t < WTAB_N) {               // w2[:,0:3] A-frags: 8 ks tiles, M=32 (pad)
        int u = t - W1F_N - W0KF_N;
        int ks = u >> 9, l = (u >> 3) & 63, j = u & 7;
        int m = l & 31;
        int k = ks * 16 + 8 * (l >> 5) + j;
        wtab[LW2 + u] = f2b(m < 3 ? w2[k * 78 + m] : 0.0f);
    }
}

// ---------------- merged: pack (8 vox/thread, plain stores) + e-prep + wtab --------
__global__ __launch_bounds__(256) void k_pack_prep(
    const float* __restrict__ dg, const float* __restrict__ pg,
    const float* __restrict__ kg, unsigned short* __restrict__ vox,
    const float* __restrict__ rays_d,
    const float* __restrict__ w0, const float* __restrict__ b0,
    const float* __restrict__ w1, const float* __restrict__ w2,
    float* __restrict__ e, unsigned short* __restrict__ wtab)
{
    const int bid = blockIdx.x;
    const int tid = threadIdx.x;
    if (bid < PACK_BLKS) {
        // ---- pack: chunk-transposed; 2 quads (8 voxels)/thread ----
        const int g   = tid & 3;
        const int s2  = tid >> 2;
        const float* pl[8];
        bool padq[8];
#pragma unroll
        for (int q = 0; q < 8; ++q) {
            int ch = 8 * g + q;
            padq[q] = (ch >= 29);
            pl[q] = (ch == 0) ? dg
                  : (ch < 17) ? pg + (size_t)(ch - 1) * CSg
                  : (ch < 29) ? kg + (size_t)(ch - 17) * CSg
                  : dg;
        }
#pragma unroll
        for (int u = 0; u < 4; ++u) {
            int va = (bid * 8 + 2 * u) * 256 + 4 * s2;
            int vb = va + 256;
            f32x4 A[8], B[8];
#pragma unroll
            for (int q = 0; q < 8; ++q)
                A[q] = __builtin_nontemporal_load((const f32x4*)(pl[q] + va));
#pragma unroll
            for (int q = 0; q < 8; ++q)
                B[q] = __builtin_nontemporal_load((const f32x4*)(pl[q] + vb));
#pragma unroll
            for (int q = 0; q < 8; ++q) {
                if (padq[q]) A[q] = f32x4{0.0f, 0.0f, 0.0f, 0.0f};
                if (padq[q]) B[q] = f32x4{0.0f, 0.0f, 0.0f, 0.0f};
            }
#pragma unroll
            for (int k = 0; k < 4; ++k) {
                int4v chunk;
#pragma unroll
                for (int h2 = 0; h2 < 4; ++h2)
                    chunk[h2] = (int)pk2(A[2 * h2][k], A[2 * h2 + 1][k]);
                *(int4v*)((char*)vox + (size_t)(va + k) * 64 + g * 16) = chunk;
            }
#pragma unroll
            for (int k = 0; k < 4; ++k) {
                int4v chunk;
#pragma unroll
                for (int h2 = 0; h2 < 4; ++h2)
                    chunk[h2] = (int)pk2(B[2 * h2][k], B[2 * h2 + 1][k]);
                *(int4v*)((char*)vox + (size_t)(vb + k) * 64 + g * 16) = chunk;
            }
        }
    } else if (bid < PACK_BLKS + EPREP_BLKS) {
        int r = (bid - PACK_BLKS) * 2 + (tid >> 7);
        eprep_body(r, tid & 127, rays_d, w0, b0, e);
    } else {
        int t = (bid - PACK_BLKS - EPREP_BLKS) * 256 + tid;
        wtab_body(t, w0, w1, w2, wtab);
    }
}

// ---------------- standalone prep (fallback path only) -----------------------------
__global__ __launch_bounds__(512) void k_prep_all(
    const float* __restrict__ rays_d,
    const float* __restrict__ w0, const float* __restrict__ b0,
    const float* __restrict__ w1, const float* __restrict__ w2,
    float* __restrict__ e, unsigned short* __restrict__ wtab)
{
    int bid = blockIdx.x;
    if (bid < R_ / 4) {
        int r = bid * 4 + (threadIdx.x >> 7);
        eprep_body(r, threadIdx.x & 127, rays_d, w0, b0, e);
    } else {
        int t = (bid - R_ / 4) * 512 + threadIdx.x;
        wtab_body(t, w0, w1, w2, wtab);
    }
}

// =============== shared helpers =====================================================
static __device__ __forceinline__ void sample_coords(
    int sid, const float* __restrict__ rays_o, const float* __restrict__ rays_d,
    int& ix, int& iy, int& iz, float& fx, float& fy, float& fz)
{
    int r = sid >> 7;
    int s = sid & 127;
    float t = s * (1.0f / 127.0f);
    float px = fminf(fmaxf(rays_o[r * 3 + 0] + rays_d[r * 3 + 0] * t, 0.0f), 1.0f);
    float py = fminf(fmaxf(rays_o[r * 3 + 1] + rays_d[r * 3 + 1] * t, 0.0f), 1.0f);
    float pz = fminf(fmaxf(rays_o[r * 3 + 2] + rays_d[r * 3 + 2] * t, 0.0f), 1.0f);
    float gx = px * (float)(NXg - 1);
    float gy = py * (float)(NYg - 1);
    float gz = pz * (float)(NZg - 1);
    ix = min((int)gx, NXg - 2);
    iy = min((int)gy, NYg - 2);
    iz = min((int)gz, NZg - 2);
    fx = gx - (float)ix;
    fy = gy - (float)iy;
    fz = gz - (float)iz;
}

static __device__ __forceinline__ float density_alpha(
    int s, const float* acc, float gfd0, const float* __restrict__ act_shift)
{
    float z = acc[0] + gfd0;
#pragma unroll
    for (int i = 0; i < 4; ++i) {
        float pa = acc[1 + 4 * i + 0], pb = acc[1 + 4 * i + 1];
        float pc = acc[1 + 4 * i + 2], pd = acc[1 + 4 * i + 3];
        float sg = 1.0f / (1.0f + expf(-pd));
        z += pa * tanhf(pb * z + pc) * sg;
    }
    float den = z + act_shift[s];
    float sp = fmaxf(den, 0.0f) + log1pf(expf(-fabsf(den)));
    return 1.0f - expf(-sp * VSRc);
}

static __device__ __forceinline__ void finish_sample(
    int sid, int s, const float* acc, float gfd0,
    const float* __restrict__ act_shift,
    float* __restrict__ alpha_ws, unsigned short* __restrict__ k0b)
{
    alpha_ws[sid] = density_alpha(s, acc, gfd0, act_shift);
    ushort8v lo, hi;
#pragma unroll
    for (int c = 0; c < 8; ++c) lo[c] = f2b(acc[17 + c]);
#pragma unroll
    for (int c = 0; c < 8; ++c) hi[c] = (c < 4) ? f2b(acc[25 + c]) : (unsigned short)0;
    *(ushort8v*)(k0b + (size_t)sid * 16)     = lo;
    *(ushort8v*)(k0b + (size_t)sid * 16 + 8) = hi;
}

// ---------------- K1a: AoS gather (grouped loads — best-measured form) -------------
__global__ __launch_bounds__(256) void k_gather_aos(
    const float* __restrict__ rays_o, const float* __restrict__ rays_d,
    const unsigned short* __restrict__ vox,
    const float* __restrict__ gfd, const float* __restrict__ act_shift,
    float* __restrict__ alpha_ws, unsigned short* __restrict__ k0b)
{
    int sid = blockIdx.x * 256 + threadIdx.x;
    if (sid >= RD) return;
    int ix, iy, iz; float fx, fy, fz;
    sample_coords(sid, rays_o, rays_d, ix, iy, iz, fx, fy, fz);

    const unsigned short* base = vox + ((size_t)(ix * NYg + iy) * NZg + iz) * 32;
    const size_t qoff[4] = { 0, (size_t)NZg * 32, (size_t)NYg * NZg * 32,
                             (size_t)(NYg + 1) * NZg * 32 };
    float wxy[4];
    wxy[0] = (1.0f - fx) * (1.0f - fy);
    wxy[1] = (1.0f - fx) * fy;
    wxy[2] = fx * (1.0f - fy);
    wxy[3] = fx * fy;
    float wz0 = 1.0f - fz, wz1 = fz;

    float acc[29];
#pragma unroll
    for (int c = 0; c < 29; ++c) acc[c] = 0.0f;

#pragma unroll
    for (int q = 0; q < 4; ++q) {
        const unsigned short* p = base + qoff[q];
#pragma unroll
        for (int dz = 0; dz < 2; ++dz) {
            float w = wxy[q] * (dz ? wz1 : wz0);
            const ushort8v* pv = (const ushort8v*)(p + dz * 32);
            ushort8v v0 = pv[0], v1 = pv[1], v2 = pv[2], v3 = pv[3];
#pragma unroll
            for (int i = 0; i < 8; ++i) acc[i]      = fmaf(w, b2f(v0[i]), acc[i]);
#pragma unroll
            for (int i = 0; i < 8; ++i) acc[8 + i]  = fmaf(w, b2f(v1[i]), acc[8 + i]);
#pragma unroll
            for (int i = 0; i < 8; ++i) acc[16 + i] = fmaf(w, b2f(v2[i]), acc[16 + i]);
#pragma unroll
            for (int i = 0; i < 5; ++i) acc[24 + i] = fmaf(w, b2f(v3[i]), acc[24 + i]);
        }
    }
    finish_sample(sid, sid & 127, acc, gfd[0] * LAMc, act_shift, alpha_ws, k0b);
}

// ---------------- K1b: SoA f32 gather (fallback when ws too small) -----------------
__global__ void k_gather_soa(
    const float* __restrict__ rays_o, const float* __restrict__ rays_d,
    const float* __restrict__ dg,  const float* __restrict__ pg,
    const float* __restrict__ kg,  const float* __restrict__ gfd,
    const float* __restrict__ act_shift,
    float* __restrict__ alpha_ws, unsigned short* __restrict__ k0b)
{
    int sid = blockIdx.x * 256 + threadIdx.x;
    if (sid >= RD) return;
    int ix, iy, iz; float fx, fy, fz;
    sample_coords(sid, rays_o, rays_d, ix, iy, iz, fx, fy, fz);

    int base = (ix * NYg + iy) * NZg + iz;
    int off[4] = { base, base + NZg, base + NYg * NZg, base + NYg * NZg + NZg };
    float wxy[4];
    wxy[0] = (1.0f - fx) * (1.0f - fy);
    wxy[1] = (1.0f - fx) * fy;
    wxy[2] = fx * (1.0f - fy);
    wxy[3] = fx * fy;
    float wz0 = 1.0f - fz, wz1 = fz;

    auto tri = [&](const float* __restrict__ g, int c) -> float {
        float a = 0.0f;
        const float* gc = g + (size_t)c * CSg;
#pragma unroll
        for (int q = 0; q < 4; ++q) {
            const float* p = gc + off[q];
            a += (p[0] * wz0 + p[1] * wz1) * wxy[q];
        }
        return a;
    };
    float acc[29];
    acc[0] = tri(dg, 0);
#pragma unroll
    for (int c = 0; c < 16; ++c) acc[1 + c] = tri(pg, c);
#pragma unroll
    for (int c = 0; c < K0C; ++c) acc[17 + c] = tri(kg, c);
    finish_sample(sid, sid & 127, acc, gfd[0] * LAMc, act_shift, alpha_ws, k0b);
}

// ---------------- K2: MFMA MLP, wave-per-ray (4 rays/block) + in-wave scan ---------
// C/D layout (32x32): col = lane&31, row = (r&3) + 8*(r>>2) + 4*(lane>>5)  [m74/m101]
struct BPair { int4v lo, hi; };
static __device__ __forceinline__ BPair ttile(const f32x16 v) {
    unsigned p[8];
#pragma unroll
    for (int q = 0; q < 8; ++q) p[q] = pk2(v[2 * q], v[2 * q + 1]);
    int2v a = __builtin_amdgcn_permlane32_swap((int)p[0], (int)p[2], false, false);
    int2v b = __builtin_amdgcn_permlane32_swap((int)p[1], (int)p[3], false, false);
    int2v c = __builtin_amdgcn_permlane32_swap((int)p[4], (int)p[6], false, false);
    int2v d = __builtin_amdgcn_permlane32_swap((int)p[5], (int)p[7], false, false);
    BPair r;
    r.lo = int4v{ a.x, b.x, a.y, b.y };
    r.hi = int4v{ c.x, d.x, c.y, d.y };
    return r;
}

__global__ __launch_bounds__(256) void k_mlp_scan4(
    const unsigned short* __restrict__ k0b, const float* __restrict__ e,
    const unsigned short* __restrict__ wtab,
    const float* __restrict__ b1, const float* __restrict__ b2,
    const float* __restrict__ gfr, const float* __restrict__ alpha_ws,
    float* __restrict__ out)
{
    __shared__ unsigned short wlds[WTAB_N];   // 45056 B, staged once per block
    __shared__ float rgb_lds[4][D_][4];       // 8192 B, wave-local strips
#pragma unroll
    for (int it = 0; it < WTAB_N / (256 * 8); ++it) {
        int i = (it * 256 + threadIdx.x) * 8;
        *(ushort8v*)&wlds[i] = *(const ushort8v*)&wtab[i];
    }
    __syncthreads();

    const int lane = threadIdx.x & 63;
    const int wid  = threadIdx.x >> 6;
    const int n    = lane & 31;
    const int h    = lane >> 5;
    const int ray  = blockIdx.x * 4 + wid;    // one wave = one ray

    for (int t = 0; t < 4; ++t) {
        const int sid = ray * D_ + t * 32 + n;

        // ---- layer 0: C-init = e[ray][.] (emb@w0[0:27]+b0), A = w0k frags ----
        f32x16 acc0[4];
#pragma unroll
        for (int mt = 0; mt < 4; ++mt) {
            const f32x4* ep = (const f32x4*)(e + (size_t)ray * WIDm + mt * 32 + 4 * h);
#pragma unroll
            for (int rr = 0; rr < 4; ++rr) {
                f32x4 ev = ep[2 * rr];
#pragma unroll
                for (int q = 0; q < 4; ++q) acc0[mt][rr * 4 + q] = ev[q];
            }
        }
        short8v bk = *(const short8v*)(k0b + (size_t)sid * 16 + h * 8);
#pragma unroll
        for (int mt = 0; mt < 4; ++mt) {
            short8v af = *(const short8v*)&wlds[LW0K + (mt * 64 + lane) * 8];
            acc0[mt] = __builtin_amdgcn_mfma_f32_32x32x16_bf16(af, bk, acc0[mt], 0, 0, 0);
        }
        int4v bw[8];
#pragma unroll
        for (int mt = 0; mt < 4; ++mt) {
            f32x16 hv;
#pragma unroll
            for (int r = 0; r < 16; ++r) hv[r] = fmaxf(acc0[mt][r], 0.0f);
            BPair tt = ttile(hv);
            bw[2 * mt]     = tt.lo;
            bw[2 * mt + 1] = tt.hi;
        }

        // ---- layer 1 ----
        f32x16 acc1[4];
#pragma unroll
        for (int mt = 0; mt < 4; ++mt) {
            const f32x4* bp = (const f32x4*)(b1 + mt * 32 + 4 * h);
#pragma unroll
            for (int rr = 0; rr < 4; ++rr) {
                f32x4 bv = bp[2 * rr];
#pragma unroll
                for (int q = 0; q < 4; ++q) acc1[mt][rr * 4 + q] = bv[q];
            }
        }
#pragma unroll
        for (int mt = 0; mt < 4; ++mt)
#pragma unroll
            for (int ks = 0; ks < 8; ++ks) {
                short8v af = *(const short8v*)&wlds[LW1 + ((mt * 8 + ks) * 64 + lane) * 8];
                acc1[mt] = __builtin_amdgcn_mfma_f32_32x32x16_bf16(af, as_s8(bw[ks]), acc1[mt], 0, 0, 0);
            }
        int4v cw[8];
#pragma unroll
        for (int mt = 0; mt < 4; ++mt) {
            f32x16 hv;
#pragma unroll
            for (int r = 0; r < 16; ++r) hv[r] = fmaxf(acc1[mt][r], 0.0f);
            BPair tt = ttile(hv);
            cw[2 * mt]     = tt.lo;
            cw[2 * mt + 1] = tt.hi;
        }

        // ---- layer 2: rgb rows 0..2 ----
        f32x16 acc2;
#pragma unroll
        for (int r = 0; r < 16; ++r) acc2[r] = 0.0f;
#pragma unroll
        for (int ks = 0; ks < 8; ++ks) {
            short8v af = *(const short8v*)&wlds[LW2 + (ks * 64 + lane) * 8];
            acc2 = __builtin_amdgcn_mfma_f32_32x32x16_bf16(af, as_s8(cw[ks]), acc2, 0, 0, 0);
        }
        if (h == 0) {   // sample t*32+n; wave-local LDS, DS in-order -> no barrier
#pragma unroll
            for (int c = 0; c < 3; ++c) {
                float v = acc2[c] + b2[c] + gfr[c] * LAMc;
                rgb_lds[wid][t * 32 + n][c] = 1.0f / (1.0f + expf(-v));
            }
        }
    }

    // ---- in-wave transmittance scan + weighted reduce ----
    int base = ray * D_ + lane * 2;
    float a0 = alpha_ws[base];
    float a1 = alpha_ws[base + 1];
    float q0 = 1.0f - a0 + 1e-10f;
    float q1 = 1.0f - a1 + 1e-10f;
    float p = q0 * q1;

    float incl = p;
#pragma unroll
    for (int o = 1; o < 64; o <<= 1) {
        float v = __shfl_up(incl, o);
        if (lane >= o) incl *= v;
    }
    float excl = __shfl_up(incl, 1);
    if (lane == 0) excl = 1.0f;
    float Tlast = __shfl(incl, 63);

    float w0s = a0 * excl;
    float w1s = a1 * excl * q0;

    float sums[3];
#pragma unroll
    for (int c = 0; c < 3; ++c) {
        float sc = w0s * rgb_lds[wid][2 * lane][c] + w1s * rgb_lds[wid][2 * lane + 1][c];
#pragma unroll
        for (int o = 32; o >= 1; o >>= 1) sc += __shfl_xor(sc, o);
        sums[c] = sc;
    }
    if (lane == 0) {
#pragma unroll
        for (int c = 0; c < 3; ++c) out[ray * 3 + c] = sums[c] + Tlast;
    }
}

extern "C" void kernel_launch(void* const* d_in, const int* in_sizes, int n_in,
                              void* d_out, int out_size, void* d_ws, size_t ws_size,
                              hipStream_t stream) {
    const float* rays_o    = (const float*)d_in[0];
    const float* rays_d    = (const float*)d_in[1];
    const float* dg        = (const float*)d_in[2];
    const float* pg        = (const float*)d_in[3];
    const float* kg        = (const float*)d_in[4];
    const float* gfd       = (const float*)d_in[5];
    const float* gfr       = (const float*)d_in[6];
    const float* w0        = (const float*)d_in[7];
    const float* b0        = (const float*)d_in[8];
    const float* w1        = (const float*)d_in[9];
    const float* b1        = (const float*)d_in[10];
    const float* w2        = (const float*)d_in[11];
    const float* b2        = (const float*)d_in[12];
    const float* act_shift = (const float*)d_in[13];
    float* out = (float*)d_out;

    float* ws = (float*)d_ws;
    float*          alpha_ws = ws;                               // RD f32
    unsigned short* k0b      = (unsigned short*)(ws + 4 * (size_t)RD);   // RD*16 u16
    float*          e_ws     = ws + 12 * (size_t)RD;             // RD f32
    unsigned short* wtab     = (unsigned short*)(ws + 13 * (size_t)RD);  // 22528 u16
    size_t frag_end = 13 * (size_t)RD * 4 + (size_t)WTAB_N * 2;
    size_t vox_off  = (frag_end + 63) & ~(size_t)63;
    unsigned short* vox = (unsigned short*)((char*)d_ws + vox_off);
    size_t need = vox_off + (size_t)CSg * 64;
    bool use_aos = (ws_size >= need);

    if (use_aos) {
        k_pack_prep<<<dim3(PACK_BLKS + EPREP_BLKS + WTAB_BLKS), dim3(256), 0, stream>>>(
            dg, pg, kg, vox, rays_d, w0, b0, w1, w2, e_ws, wtab);
        k_gather_aos<<<dim3(RD / 256), dim3(256), 0, stream>>>(
            rays_o, rays_d, vox, gfd, act_shift, alpha_ws, k0b);
    } else {
        k_prep_all<<<dim3(R_ / 4 + (WTAB_N + 511) / 512), dim3(512), 0, stream>>>(
            rays_d, w0, b0, w1, w2, e_ws, wtab);
        k_gather_soa<<<dim3(RD / 256), dim3(256), 0, stream>>>(
            rays_o, rays_d, dg, pg, kg, gfd, act_shift, alpha_ws, k0b);
    }
    k_mlp_scan4<<<dim3(R_ / 4), dim3(256), 0, stream>>>(
        k0b, e_ws, wtab, b1, b2, gfr, alpha_ws, out);
}